// Round 1
// 2238.251 us; speedup vs baseline: 1.3384x; 1.3384x over previous
//
#include <hip/hip_runtime.h>
#include <hip/hip_bf16.h>
#include <cstdint>

// Problem constants (fixed by reference)
#define Bsz   64
#define Nsz   1024
#define D2    1024   // 2*NHID
#define D3    1536   // 3*NHID
#define DA_   350
#define R_    30
#define MLPH  2048
#define KMLP  46080  // R*3*NHID
#define S1LD  352    // padded leading dim for s1 buffer
#define NKB   16     // split-K factor for MLP GEMM

// ---------- dtype-agnostic load/store helpers (bf = 1 -> packed bf16) ----------
__device__ __forceinline__ float ub2f(unsigned short u) {
  union { float f; unsigned v; } c; c.v = ((unsigned)u) << 16; return c.f;
}
__device__ __forceinline__ unsigned short f2ub(float f) {
  union { float f; unsigned v; } c; c.f = f;
  unsigned v = c.v;
  return (unsigned short)((v + 0x7FFFu + ((v >> 16) & 1u)) >> 16);  // RNE
}
__device__ __forceinline__ float ld1(const void* p, size_t i, int bf) {
  return bf ? ub2f(((const unsigned short*)p)[i]) : ((const float*)p)[i];
}
__device__ __forceinline__ void ld4(const void* p, size_t i, int bf, float* o) {
  if (bf) {
    ushort4 v = *(const ushort4*)((const unsigned short*)p + i);
    o[0] = ub2f(v.x); o[1] = ub2f(v.y); o[2] = ub2f(v.z); o[3] = ub2f(v.w);
  } else {
    float4 v = *(const float4*)((const float*)p + i);
    o[0] = v.x; o[1] = v.y; o[2] = v.z; o[3] = v.w;
  }
}
__device__ __forceinline__ void st1(void* p, size_t i, int bf, float v) {
  if (bf) ((unsigned short*)p)[i] = f2ub(v);
  else    ((float*)p)[i] = v;
}

// ---------- 0: dtype probe ----------
__global__ void k_detect(const void* __restrict__ enc, int* __restrict__ flag) {
  const unsigned* u = (const unsigned*)enc;
  unsigned x = u[threadIdx.x];
  unsigned e = (x >> 7) & 0xFFu;
  bool hit = (e >= 118u && e <= 132u);
  unsigned long long b = __ballot(hit);
  if (threadIdx.x == 0) *flag = (__popcll(b) > 32) ? 1 : 0;
}

// ---------- 0.5: catW1[b][a] = sum_{k<512} cat[b,k] * W1[a, 1024+k]  (hoists the
// broadcast third of the s1 K-loop: identical for all 1024 n of a batch) ----------
__global__ __launch_bounds__(256) void k_cat(const void* __restrict__ cat,
                                             const void* __restrict__ W1,
                                             float* __restrict__ catW1,
                                             const int* __restrict__ flagp) {
  const int bf = *flagp;
  const int a = blockIdx.x;  // 0..349
  __shared__ float wsh[512];
  for (int i = threadIdx.x; i < 512; i += 256) wsh[i] = ld1(W1, (size_t)a * D3 + D2 + i, bf);
  __syncthreads();
  const int b = threadIdx.x >> 2, q = threadIdx.x & 3;
  const size_t cb = (size_t)b * 512 + q * 128;
  float p = 0.f;
  for (int k = 0; k < 128; k += 4) {
    float o[4]; ld4(cat, cb + k, bf, o);
    const int w = q * 128 + k;
    p += o[0] * wsh[w] + o[1] * wsh[w + 1] + o[2] * wsh[w + 2] + o[3] * wsh[w + 3];
  }
  p += __shfl_xor(p, 1); p += __shfl_xor(p, 2);
  if (q == 0) catW1[(size_t)b * DA_ + a] = p;
}

// ---------- 1: s1[m,a] = tanh(sum_{k<1024} enc[m,k]*W1[a,k] + catW1[b,a]) ----------
// 128x128 block tile, 8x8 per-thread micro-tile (split-half fragments: rows
// {ty*4..+3, 64+ty*4..+3}, cols {tx*4..+3, 64+tx*4..+3} -> all LDS reads <=2-way).
// Staging: [k][m] layout, row = tid>>1 -> b32 writes are 2-way (free).
// XCD swizzle: 1536 blocks = 8 XCD * (64 m-blocks * 3 a-siblings) so the 3
// a-siblings sharing enc rows land on the same XCD's L2.
__global__ __launch_bounds__(256, 4) void k_s1(const void* __restrict__ enc,
                                               const void* __restrict__ W1,
                                               const float* __restrict__ catW1,
                                               float* __restrict__ s1,
                                               const int* __restrict__ flagp) {
  const int bf = *flagp;
  __shared__ float As[16][128];
  __shared__ float Bs[16][128];
  const int id   = blockIdx.y * 3 + blockIdx.x;  // linear dispatch id, x fastest
  const int xcd  = id & 7;
  const int ixcd = id >> 3;                       // 0..191
  const int a0   = (ixcd % 3) * 128;
  const int m0   = (xcd * 64 + ixcd / 3) * 128;   // bijective over 512 m-blocks
  const int tid = threadIdx.x;
  const int tx = tid & 15, ty = tid >> 4;
  const int row = tid >> 1;
  const int ko  = (tid & 1) * 8;
  const int gm = m0 + row;
  const int ga = a0 + row;
  const bool bvalid = (ga < DA_);
  float acc[8][8] = {};
  for (int k0 = 0; k0 < D2; k0 += 16) {
    {
      float o[8];
      const size_t base = (size_t)gm * D2 + k0 + ko;
      ld4(enc, base, bf, o); ld4(enc, base + 4, bf, o + 4);
#pragma unroll
      for (int j = 0; j < 8; ++j) As[ko + j][row] = o[j];
    }
    {
      float o[8] = {};
      if (bvalid) {
        const size_t base = (size_t)ga * D3 + k0 + ko;
        ld4(W1, base, bf, o); ld4(W1, base + 4, bf, o + 4);
      }
#pragma unroll
      for (int j = 0; j < 8; ++j) Bs[ko + j][row] = o[j];
    }
    __syncthreads();
#pragma unroll
    for (int kk = 0; kk < 16; ++kk) {
      float4 ra0 = *(const float4*)&As[kk][ty * 4];
      float4 ra1 = *(const float4*)&As[kk][64 + ty * 4];
      float4 rb0 = *(const float4*)&Bs[kk][tx * 4];
      float4 rb1 = *(const float4*)&Bs[kk][64 + tx * 4];
      float av[8] = {ra0.x, ra0.y, ra0.z, ra0.w, ra1.x, ra1.y, ra1.z, ra1.w};
      float bv[8] = {rb0.x, rb0.y, rb0.z, rb0.w, rb1.x, rb1.y, rb1.z, rb1.w};
#pragma unroll
      for (int i = 0; i < 8; ++i)
#pragma unroll
        for (int j = 0; j < 8; ++j) acc[i][j] += av[i] * bv[j];
    }
    __syncthreads();
  }
  const int bb = m0 >> 10;  // batch index (128-row tiles never cross a batch)
  float cj[8];
#pragma unroll
  for (int j = 0; j < 8; ++j) {
    const int a = a0 + ((j < 4) ? (tx * 4 + j) : (64 + tx * 4 + j - 4));
    cj[j] = (a < DA_) ? catW1[(size_t)bb * DA_ + a] : 0.f;
  }
#pragma unroll
  for (int i = 0; i < 8; ++i) {
    const int m = m0 + ((i < 4) ? (ty * 4 + i) : (64 + ty * 4 + i - 4));
    float* srow = s1 + (size_t)m * S1LD;
#pragma unroll
    for (int j = 0; j < 8; ++j) {
      const int a = a0 + ((j < 4) ? (tx * 4 + j) : (64 + tx * 4 + j - 4));
      if (a < DA_) srow[a] = tanhf(acc[i][j] + cj[j]);
    }
  }
}

// ---------- 2: scores[b,r,n] = masked( sum_a s1[m,a]*W2[r,a] ) -> Aws (fp32) ----------
__global__ __launch_bounds__(256) void k_s2(const float* __restrict__ s1,
                                            const void* __restrict__ W2,
                                            const int* __restrict__ lens,
                                            float* __restrict__ Aws,
                                            const int* __restrict__ flagp) {
  const int bf = *flagp;
  __shared__ float w2s[R_ * DA_];  // 42 KB
  for (int i = threadIdx.x; i < R_ * DA_; i += 256) w2s[i] = ld1(W2, i, bf);
  __syncthreads();
  const int g = blockIdx.x * 256 + threadIdx.x;
  const int m = g >> 5;       // 32 threads per row (30 active)
  const int r = g & 31;
  if (r >= R_) return;
  const float* row = s1 + (size_t)m * S1LD;
  const float* w = &w2s[r * DA_];
  float acc = 0.f;
#pragma unroll 2
  for (int a = 0; a < DA_; ++a) acc += row[a] * w[a];
  const int b = m >> 10, n = m & 1023;
  const float val = (n < lens[b]) ? acc : -1e9f;
  Aws[((size_t)b * R_ + r) * Nsz + n] = val;
}

// ---------- 3: softmax over n, in-place on Aws; also emit A output ----------
__global__ __launch_bounds__(256) void k_softmax(float* __restrict__ Aws,
                                                 void* __restrict__ dout,
                                                 const int* __restrict__ flagp) {
  const int bf = *flagp;
  const int row = blockIdx.x;  // b*30 + r, 1920 rows
  float* p = Aws + (size_t)row * Nsz;
  const int tid = threadIdx.x;
  float4 v = ((const float4*)p)[tid];
  float mx = fmaxf(fmaxf(v.x, v.y), fmaxf(v.z, v.w));
#pragma unroll
  for (int off = 1; off < 64; off <<= 1) mx = fmaxf(mx, __shfl_xor(mx, off));
  __shared__ float sred[4], sred2[4];
  if ((tid & 63) == 0) sred[tid >> 6] = mx;
  __syncthreads();
  mx = fmaxf(fmaxf(sred[0], sred[1]), fmaxf(sred[2], sred[3]));
  float e0 = __expf(v.x - mx), e1 = __expf(v.y - mx);
  float e2 = __expf(v.z - mx), e3 = __expf(v.w - mx);
  float s = e0 + e1 + e2 + e3;
#pragma unroll
  for (int off = 1; off < 64; off <<= 1) s += __shfl_xor(s, off);
  if ((tid & 63) == 0) sred2[tid >> 6] = s;
  __syncthreads();
  s = sred2[0] + sred2[1] + sred2[2] + sred2[3];
  const float inv = 1.0f / s;
  const float o0 = e0 * inv, o1 = e1 * inv, o2 = e2 * inv, o3 = e3 * inv;
  ((float4*)p)[tid] = make_float4(o0, o1, o2, o3);
  const size_t base = (size_t)Bsz * MLPH + (size_t)row * Nsz + (size_t)tid * 4;
  st1(dout, base + 0, bf, o0); st1(dout, base + 1, bf, o1);
  st1(dout, base + 2, bf, o2); st1(dout, base + 3, bf, o3);
}

// ---------- 4: M[b,r,d] = sum_n A[b,r,n] * HV[b,n,d] ----------
// d >= 1024: sum_n A = 1 exactly (softmax) -> M = cat[b][d-1024], no reduction.
__global__ __launch_bounds__(256) void k_M(const float* __restrict__ Aws,
                                           const void* __restrict__ enc,
                                           const void* __restrict__ cat,
                                           float* __restrict__ Mf,
                                           const int* __restrict__ flagp) {
  const int bf = *flagp;
  const int b = blockIdx.y;
  const int d0 = blockIdx.x * 128;
  const int tid = threadIdx.x;
  const int dcol = d0 + (tid & 127);
  const int half = tid >> 7;  // 0/1 -> r in [half*15, half*15+15)
  if (d0 >= D2) {             // block-uniform fast path (no barriers inside)
    const float hv = ld1(cat, (size_t)b * 512 + (dcol - D2), bf);
#pragma unroll
    for (int i = 0; i < 15; ++i) {
      const int r = half * 15 + i;
      Mf[((size_t)b * R_ + r) * D3 + dcol] = hv;
    }
    return;
  }
  __shared__ float Ash[R_][64];
  float acc[15] = {};
  const float* Ab = Aws + (size_t)b * R_ * Nsz;
  for (int n0 = 0; n0 < Nsz; n0 += 64) {
    for (int idx = tid; idx < R_ * 64; idx += 256) {
      const int r = idx >> 6, nn = idx & 63;
      Ash[r][nn] = Ab[(size_t)r * Nsz + n0 + nn];
    }
    __syncthreads();
    {
      const size_t base = ((size_t)b * Nsz + n0) * D2 + dcol;
      for (int nn = 0; nn < 64; ++nn) {
        const float hv = ld1(enc, base + (size_t)nn * D2, bf);
#pragma unroll
        for (int i = 0; i < 15; ++i) acc[i] += Ash[half * 15 + i][nn] * hv;
      }
    }
    __syncthreads();
  }
#pragma unroll
  for (int i = 0; i < 15; ++i) {
    const int r = half * 15 + i;
    Mf[((size_t)b * R_ + r) * D3 + dcol] = acc[i];
  }
}

// ---------- 5: split-K MLP GEMM: part[kb][b][j] = sum_{k in chunk} M[b,k] * W_mlp[j,k] ----------
__global__ __launch_bounds__(256) void k_mlp(const float* __restrict__ Mf,   // [64][46080] fp32
                                             const void* __restrict__ Wm,   // [2048][46080]
                                             float* __restrict__ part,      // [NKB][64][2048]
                                             const int* __restrict__ flagp) {
  const int bf = *flagp;
  const int j0 = blockIdx.x * 32;
  const int kb = blockIdx.y;
  const int kbeg = kb * (KMLP / NKB);
  const int kend = kbeg + (KMLP / NKB);
  __shared__ float Ms[32][64];  // [k][b]
  __shared__ float Ws[32][32];  // [k][j]
  const int tid = threadIdx.x;
  const int tx = tid & 15, ty = tid >> 4;
  float acc[4][2] = {};
  for (int k0 = kbeg; k0 < kend; k0 += 32) {
    {
      const int boff = tid >> 3;
      const int koff = (tid & 7) * 4;
#pragma unroll
      for (int p = 0; p < 2; ++p) {
        const int bb = boff + p * 32;
        float4 v = *(const float4*)(Mf + (size_t)bb * KMLP + k0 + koff);
        Ms[koff + 0][bb] = v.x; Ms[koff + 1][bb] = v.y;
        Ms[koff + 2][bb] = v.z; Ms[koff + 3][bb] = v.w;
      }
    }
    {
      const int joff = tid >> 3;
      const int koff = (tid & 7) * 4;
      float o[4];
      ld4(Wm, (size_t)(j0 + joff) * KMLP + k0 + koff, bf, o);
      Ws[koff + 0][joff] = o[0]; Ws[koff + 1][joff] = o[1];
      Ws[koff + 2][joff] = o[2]; Ws[koff + 3][joff] = o[3];
    }
    __syncthreads();
#pragma unroll
    for (int kk = 0; kk < 32; ++kk) {
      float4 rm = *(const float4*)&Ms[kk][ty * 4];
      const float w0 = Ws[kk][tx * 2], w1 = Ws[kk][tx * 2 + 1];
      acc[0][0] += rm.x * w0; acc[0][1] += rm.x * w1;
      acc[1][0] += rm.y * w0; acc[1][1] += rm.y * w1;
      acc[2][0] += rm.z * w0; acc[2][1] += rm.z * w1;
      acc[3][0] += rm.w * w0; acc[3][1] += rm.w * w1;
    }
    __syncthreads();
  }
#pragma unroll
  for (int i = 0; i < 4; ++i) {
    const int bb = ty * 4 + i;
    part[((size_t)kb * Bsz + bb) * MLPH + j0 + tx * 2 + 0] = acc[i][0];
    part[((size_t)kb * Bsz + bb) * MLPH + j0 + tx * 2 + 1] = acc[i][1];
  }
}

// ---------- 6: out[b,j] = b_mlp[j] + sum_kb part[kb][b][j] ----------
__global__ __launch_bounds__(256) void k_out(const float* __restrict__ part,
                                             const void* __restrict__ bias,
                                             void* __restrict__ dout,
                                             const int* __restrict__ flagp) {
  const int bf = *flagp;
  const int g = blockIdx.x * 256 + threadIdx.x;  // < 131072
  const int j = g & (MLPH - 1);
  float v = ld1(bias, j, bf);
#pragma unroll
  for (int kb = 0; kb < NKB; ++kb) v += part[(size_t)kb * Bsz * MLPH + g];
  st1(dout, g, bf, v);
}

extern "C" void kernel_launch(void* const* d_in, const int* in_sizes, int n_in,
                              void* d_out, int out_size, void* d_ws, size_t ws_size,
                              hipStream_t stream) {
  const void* enc  = d_in[0];                 // [64,1024,1024]
  const int*  lens = (const int*)d_in[1];     // [64]
  const void* cat  = d_in[3];                 // [64,1,512]
  const void* W1   = d_in[4];                 // [350,1536]
  const void* W2   = d_in[5];                 // [30,350]
  const void* Wm   = d_in[6];                 // [2048,46080]
  const void* bmlp = d_in[7];                 // [2048]

  // workspace layout (~114.1 MB, unchanged footprint)
  char*  wsb  = (char*)d_ws;
  int*   flag = (int*)wsb;
  float* s1   = (float*)(wsb + 1024);                    // 65536*352 fp32 = 92.27 MB
  float* Aws  = s1 + (size_t)65536 * S1LD;               // 64*30*1024 fp32 = 7.86 MB
  float* Mf   = Aws + (size_t)Bsz * R_ * Nsz;            // 64*46080 fp32 = 11.80 MB
  // aliases into dead regions (stream-ordered, no overlap in lifetime):
  float* catW1 = Aws;   // written by k_cat, read by k_s1; Aws written later by k_s2
  float* part  = s1;    // s1 is dead after k_s2; part (NKB*64*2048 fp32 = 8.4 MB) fits

  k_detect <<<1, 64, 0, stream>>>(enc, flag);
  k_cat    <<<DA_, 256, 0, stream>>>(cat, W1, catW1, flag);
  k_s1     <<<dim3(3, 512), 256, 0, stream>>>(enc, W1, catW1, s1, flag);
  k_s2     <<<8192, 256, 0, stream>>>(s1, W2, lens, Aws, flag);
  k_softmax<<<Bsz * R_, 256, 0, stream>>>(Aws, d_out, flag);
  k_M      <<<dim3(12, Bsz), 256, 0, stream>>>(Aws, enc, cat, Mf, flag);
  k_mlp    <<<dim3(MLPH / 32, NKB), 256, 0, stream>>>(Mf, Wm, part, flag);
  k_out    <<<512, 256, 0, stream>>>(part, bmlp, d_out, flag);
}

// Round 2
// 1690.789 us; speedup vs baseline: 1.7718x; 1.3238x over previous
//
#include <hip/hip_runtime.h>
#include <hip/hip_bf16.h>
#include <cstdint>

// Problem constants (fixed by reference)
#define Bsz   64
#define Nsz   1024
#define D2    1024   // 2*NHID
#define D3    1536   // 3*NHID
#define DA_   350
#define R_    30
#define MLPH  2048
#define KMLP  46080  // R*3*NHID
#define S1LD  352    // padded leading dim for s1 buffer
#define NKB   32     // split-K factor for MLP GEMM

// ---------- dtype-agnostic load/store helpers (bf = 1 -> packed bf16) ----------
__device__ __forceinline__ float ub2f(unsigned short u) {
  union { float f; unsigned v; } c; c.v = ((unsigned)u) << 16; return c.f;
}
__device__ __forceinline__ unsigned short f2ub(float f) {
  union { float f; unsigned v; } c; c.f = f;
  unsigned v = c.v;
  return (unsigned short)((v + 0x7FFFu + ((v >> 16) & 1u)) >> 16);  // RNE
}
__device__ __forceinline__ float ld1(const void* p, size_t i, int bf) {
  return bf ? ub2f(((const unsigned short*)p)[i]) : ((const float*)p)[i];
}
__device__ __forceinline__ void ld2(const void* p, size_t i, int bf, float* o) {
  if (bf) {
    ushort2 v = *(const ushort2*)((const unsigned short*)p + i);
    o[0] = ub2f(v.x); o[1] = ub2f(v.y);
  } else {
    float2 v = *(const float2*)((const float*)p + i);
    o[0] = v.x; o[1] = v.y;
  }
}
__device__ __forceinline__ void ld4(const void* p, size_t i, int bf, float* o) {
  if (bf) {
    ushort4 v = *(const ushort4*)((const unsigned short*)p + i);
    o[0] = ub2f(v.x); o[1] = ub2f(v.y); o[2] = ub2f(v.z); o[3] = ub2f(v.w);
  } else {
    float4 v = *(const float4*)((const float*)p + i);
    o[0] = v.x; o[1] = v.y; o[2] = v.z; o[3] = v.w;
  }
}
__device__ __forceinline__ void st1(void* p, size_t i, int bf, float v) {
  if (bf) ((unsigned short*)p)[i] = f2ub(v);
  else    ((float*)p)[i] = v;
}

// ---------- 0: dtype probe ----------
__global__ void k_detect(const void* __restrict__ enc, int* __restrict__ flag) {
  const unsigned* u = (const unsigned*)enc;
  unsigned x = u[threadIdx.x];
  unsigned e = (x >> 7) & 0xFFu;
  bool hit = (e >= 118u && e <= 132u);
  unsigned long long b = __ballot(hit);
  if (threadIdx.x == 0) *flag = (__popcll(b) > 32) ? 1 : 0;
}

// ---------- 0.5: catW1[b][a] = sum_{k<512} cat[b,k] * W1[a, 1024+k] ----------
__global__ __launch_bounds__(256) void k_cat(const void* __restrict__ cat,
                                             const void* __restrict__ W1,
                                             float* __restrict__ catW1,
                                             const int* __restrict__ flagp) {
  const int bf = *flagp;
  const int a = blockIdx.x;  // 0..349
  __shared__ float wsh[512];
  for (int i = threadIdx.x; i < 512; i += 256) wsh[i] = ld1(W1, (size_t)a * D3 + D2 + i, bf);
  __syncthreads();
  const int b = threadIdx.x >> 2, q = threadIdx.x & 3;
  const size_t cb = (size_t)b * 512 + q * 128;
  float p = 0.f;
  for (int k = 0; k < 128; k += 4) {
    float o[4]; ld4(cat, cb + k, bf, o);
    const int w = q * 128 + k;
    p += o[0] * wsh[w] + o[1] * wsh[w + 1] + o[2] * wsh[w + 2] + o[3] * wsh[w + 3];
  }
  p += __shfl_xor(p, 1); p += __shfl_xor(p, 2);
  if (q == 0) catW1[(size_t)b * DA_ + a] = p;
}

// ---------- 1: s1[m,a] = tanh(sum_{k<1024} enc[m,k]*W1[a,k] + catW1[b,a]) ----------
// 128x128 tile, 8x8 micro-tile. NO min-waves launch bound: the 8x8 acc needs
// ~110 VGPRs; forcing 4 waves/EU capped at 64 and spilled acc to scratch
// (observed WRITE_SIZE 935 MB = 10x output). Length skip: tiles whose whole
// n-range is masked feed only softmax-0 weights -> exit (block-uniform).
__global__ __launch_bounds__(256) void k_s1(const void* __restrict__ enc,
                                            const void* __restrict__ W1,
                                            const float* __restrict__ catW1,
                                            const int* __restrict__ lens,
                                            float* __restrict__ s1,
                                            const int* __restrict__ flagp) {
  const int bf = *flagp;
  __shared__ float As[16][128];
  __shared__ float Bs[16][128];
  const int id   = blockIdx.y * 3 + blockIdx.x;  // linear dispatch id, x fastest
  const int xcd  = id & 7;
  const int ixcd = id >> 3;                       // 0..191
  const int a0   = (ixcd % 3) * 128;
  const int m0   = (xcd * 64 + ixcd / 3) * 128;   // bijective over 512 m-blocks
  const int bb   = m0 >> 10;                      // batch (tiles never cross batch)
  if ((m0 & 1023) >= lens[bb]) return;            // fully-masked tile: skip
  const int tid = threadIdx.x;
  const int tx = tid & 15, ty = tid >> 4;
  const int row = tid >> 1;
  const int ko  = (tid & 1) * 8;
  const int gm = m0 + row;
  const int ga = a0 + row;
  const bool bvalid = (ga < DA_);
  float acc[8][8] = {};
  for (int k0 = 0; k0 < D2; k0 += 16) {
    {
      float o[8];
      const size_t base = (size_t)gm * D2 + k0 + ko;
      ld4(enc, base, bf, o); ld4(enc, base + 4, bf, o + 4);
#pragma unroll
      for (int j = 0; j < 8; ++j) As[ko + j][row] = o[j];
    }
    {
      float o[8] = {};
      if (bvalid) {
        const size_t base = (size_t)ga * D3 + k0 + ko;
        ld4(W1, base, bf, o); ld4(W1, base + 4, bf, o + 4);
      }
#pragma unroll
      for (int j = 0; j < 8; ++j) Bs[ko + j][row] = o[j];
    }
    __syncthreads();
#pragma unroll
    for (int kk = 0; kk < 16; ++kk) {
      float4 ra0 = *(const float4*)&As[kk][ty * 4];
      float4 ra1 = *(const float4*)&As[kk][64 + ty * 4];
      float4 rb0 = *(const float4*)&Bs[kk][tx * 4];
      float4 rb1 = *(const float4*)&Bs[kk][64 + tx * 4];
      float av[8] = {ra0.x, ra0.y, ra0.z, ra0.w, ra1.x, ra1.y, ra1.z, ra1.w};
      float bv[8] = {rb0.x, rb0.y, rb0.z, rb0.w, rb1.x, rb1.y, rb1.z, rb1.w};
#pragma unroll
      for (int i = 0; i < 8; ++i)
#pragma unroll
        for (int j = 0; j < 8; ++j) acc[i][j] += av[i] * bv[j];
    }
    __syncthreads();
  }
  float cj[8];
#pragma unroll
  for (int j = 0; j < 8; ++j) {
    const int a = a0 + ((j < 4) ? (tx * 4 + j) : (64 + tx * 4 + j - 4));
    cj[j] = (a < DA_) ? catW1[(size_t)bb * DA_ + a] : 0.f;
  }
#pragma unroll
  for (int i = 0; i < 8; ++i) {
    const int m = m0 + ((i < 4) ? (ty * 4 + i) : (64 + ty * 4 + i - 4));
    float* srow = s1 + (size_t)m * S1LD;
#pragma unroll
    for (int j = 0; j < 8; ++j) {
      const int a = a0 + ((j < 4) ? (tx * 4 + j) : (64 + tx * 4 + j - 4));
      if (a < DA_) srow[a] = tanhf(acc[i][j] + cj[j]);
    }
  }
}

// ---------- 2: scores[b,r,n] = masked( sum_a s1[m,a]*W2[r,a] ) -> Aws (fp32) ----------
// Masked rows short-circuit BEFORE touching s1 (those s1 tiles were skipped and
// hold garbage; it must never enter a live value).
__global__ __launch_bounds__(256) void k_s2(const float* __restrict__ s1,
                                            const void* __restrict__ W2,
                                            const int* __restrict__ lens,
                                            float* __restrict__ Aws,
                                            const int* __restrict__ flagp) {
  const int bf = *flagp;
  __shared__ float w2s[R_ * DA_];  // 42 KB
  for (int i = threadIdx.x; i < R_ * DA_; i += 256) w2s[i] = ld1(W2, i, bf);
  __syncthreads();
  const int g = blockIdx.x * 256 + threadIdx.x;
  const int m = g >> 5;       // 32 threads per row (30 active)
  const int r = g & 31;
  if (r >= R_) return;
  const int b = m >> 10, n = m & 1023;
  if (n >= lens[b]) { Aws[((size_t)b * R_ + r) * Nsz + n] = -1e9f; return; }
  const float* row = s1 + (size_t)m * S1LD;
  const float* w = &w2s[r * DA_];
  float acc = 0.f;
  for (int a = 0; a < 348; a += 4) {
    float4 v = *(const float4*)(row + a);
    acc += v.x * w[a] + v.y * w[a + 1] + v.z * w[a + 2] + v.w * w[a + 3];
  }
  acc += row[348] * w[348] + row[349] * w[349];
  Aws[((size_t)b * R_ + r) * Nsz + n] = acc;
}

// ---------- 3: softmax over n, in-place on Aws; also emit A output ----------
__global__ __launch_bounds__(256) void k_softmax(float* __restrict__ Aws,
                                                 void* __restrict__ dout,
                                                 const int* __restrict__ flagp) {
  const int bf = *flagp;
  const int row = blockIdx.x;  // b*30 + r, 1920 rows
  float* p = Aws + (size_t)row * Nsz;
  const int tid = threadIdx.x;
  float4 v = ((const float4*)p)[tid];
  float mx = fmaxf(fmaxf(v.x, v.y), fmaxf(v.z, v.w));
#pragma unroll
  for (int off = 1; off < 64; off <<= 1) mx = fmaxf(mx, __shfl_xor(mx, off));
  __shared__ float sred[4], sred2[4];
  if ((tid & 63) == 0) sred[tid >> 6] = mx;
  __syncthreads();
  mx = fmaxf(fmaxf(sred[0], sred[1]), fmaxf(sred[2], sred[3]));
  float e0 = __expf(v.x - mx), e1 = __expf(v.y - mx);
  float e2 = __expf(v.z - mx), e3 = __expf(v.w - mx);
  float s = e0 + e1 + e2 + e3;
#pragma unroll
  for (int off = 1; off < 64; off <<= 1) s += __shfl_xor(s, off);
  if ((tid & 63) == 0) sred2[tid >> 6] = s;
  __syncthreads();
  s = sred2[0] + sred2[1] + sred2[2] + sred2[3];
  const float inv = 1.0f / s;
  const float o0 = e0 * inv, o1 = e1 * inv, o2 = e2 * inv, o3 = e3 * inv;
  ((float4*)p)[tid] = make_float4(o0, o1, o2, o3);
  const size_t base = (size_t)Bsz * MLPH + (size_t)row * Nsz + (size_t)tid * 4;
  st1(dout, base + 0, bf, o0); st1(dout, base + 1, bf, o1);
  st1(dout, base + 2, bf, o2); st1(dout, base + 3, bf, o3);
}

// ---------- 4: M[b,r,d] = sum_n A[b,r,n] * HV[b,n,d] ----------
// d >= 1024: sum_n A = 1 exactly -> M = cat[b][d-1024]. n-loop capped at
// ceil(len/64) stages: A is exactly 0 for masked n.
__global__ __launch_bounds__(256) void k_M(const float* __restrict__ Aws,
                                           const void* __restrict__ enc,
                                           const void* __restrict__ cat,
                                           const int* __restrict__ lens,
                                           float* __restrict__ Mf,
                                           const int* __restrict__ flagp) {
  const int bf = *flagp;
  const int b = blockIdx.y;
  const int x = blockIdx.x;      // 0..3 enc halves of 256 cols, 4..5 cat
  const int tid = threadIdx.x;
  const int half = tid >> 7;     // 0/1 -> r in [half*15, half*15+15)
  const int lane = tid & 127;
  if (x >= 4) {                  // block-uniform cat fast path
    const int dc = (x - 4) * 256 + lane * 2;
    float o[2];
    ld2(cat, (size_t)b * 512 + dc, bf, o);
#pragma unroll
    for (int i = 0; i < 15; ++i) {
      const int r = half * 15 + i;
      float* mp = Mf + ((size_t)b * R_ + r) * D3 + 1024 + dc;
      mp[0] = o[0]; mp[1] = o[1];
    }
    return;
  }
  const int dcol = x * 256 + lane * 2;
  __shared__ float Ash[R_][64];
  float acc0[15] = {}, acc1[15] = {};
  const float* Ab = Aws + (size_t)b * R_ * Nsz;
  const int nstages = (lens[b] + 63) >> 6;
  for (int s = 0; s < nstages; ++s) {
    const int n0 = s * 64;
    for (int idx = tid; idx < R_ * 64; idx += 256) {
      const int r = idx >> 6, nn = idx & 63;
      Ash[r][nn] = Ab[(size_t)r * Nsz + n0 + nn];
    }
    __syncthreads();
    const size_t base = ((size_t)b * Nsz + n0) * D2 + dcol;
    for (int nn = 0; nn < 64; ++nn) {
      float h[2];
      ld2(enc, base + (size_t)nn * D2, bf, h);
#pragma unroll
      for (int i = 0; i < 15; ++i) {
        const float a = Ash[half * 15 + i][nn];
        acc0[i] += a * h[0]; acc1[i] += a * h[1];
      }
    }
    __syncthreads();
  }
#pragma unroll
  for (int i = 0; i < 15; ++i) {
    const int r = half * 15 + i;
    float* mp = Mf + ((size_t)b * R_ + r) * D3 + dcol;
    mp[0] = acc0[i]; mp[1] = acc1[i];
  }
}

// ---------- 5: split-K MLP GEMM, 64x64 tile, 4x4 micro ----------
__global__ __launch_bounds__(256) void k_mlp(const float* __restrict__ Mf,   // [64][46080] fp32
                                             const void* __restrict__ Wm,   // [2048][46080]
                                             float* __restrict__ part,      // [NKB][64][2048]
                                             const int* __restrict__ flagp) {
  const int bf = *flagp;
  const int j0 = blockIdx.x * 64;
  const int kb = blockIdx.y;
  const int kbeg = kb * (KMLP / NKB);     // chunk = 1440
  const int kend = kbeg + (KMLP / NKB);
  __shared__ float Ms[32][64];  // [k][b]
  __shared__ float Ws[32][64];  // [k][j]
  const int tid = threadIdx.x;
  const int tx = tid & 15, ty = tid >> 4;
  float acc[4][4] = {};
  for (int k0 = kbeg; k0 < kend; k0 += 32) {
    {
      const int boff = tid >> 3;
      const int koff = (tid & 7) * 4;
#pragma unroll
      for (int p = 0; p < 2; ++p) {
        const int bb = boff + p * 32;
        float4 v = *(const float4*)(Mf + (size_t)bb * KMLP + k0 + koff);
        Ms[koff + 0][bb] = v.x; Ms[koff + 1][bb] = v.y;
        Ms[koff + 2][bb] = v.z; Ms[koff + 3][bb] = v.w;
      }
    }
    {
      const int joff = tid >> 3;
      const int koff = (tid & 7) * 4;
#pragma unroll
      for (int p = 0; p < 2; ++p) {
        const int jj = joff + p * 32;
        float o[4];
        ld4(Wm, (size_t)(j0 + jj) * KMLP + k0 + koff, bf, o);
        Ws[koff + 0][jj] = o[0]; Ws[koff + 1][jj] = o[1];
        Ws[koff + 2][jj] = o[2]; Ws[koff + 3][jj] = o[3];
      }
    }
    __syncthreads();
#pragma unroll
    for (int kk = 0; kk < 32; ++kk) {
      float4 rm = *(const float4*)&Ms[kk][ty * 4];
      float4 rw = *(const float4*)&Ws[kk][tx * 4];
      float mv[4] = {rm.x, rm.y, rm.z, rm.w};
      float wv[4] = {rw.x, rw.y, rw.z, rw.w};
#pragma unroll
      for (int i = 0; i < 4; ++i)
#pragma unroll
        for (int j = 0; j < 4; ++j) acc[i][j] += mv[i] * wv[j];
    }
    __syncthreads();
  }
#pragma unroll
  for (int i = 0; i < 4; ++i) {
    const int bb = ty * 4 + i;
    float4 v = make_float4(acc[i][0], acc[i][1], acc[i][2], acc[i][3]);
    *(float4*)&part[((size_t)kb * Bsz + bb) * MLPH + j0 + tx * 4] = v;
  }
}

// ---------- 6: out[b,j] = b_mlp[j] + sum_kb part[kb][b][j] ----------
__global__ __launch_bounds__(256) void k_out(const float* __restrict__ part,
                                             const void* __restrict__ bias,
                                             void* __restrict__ dout,
                                             const int* __restrict__ flagp) {
  const int bf = *flagp;
  const int g = blockIdx.x * 256 + threadIdx.x;  // < 131072
  const int j = g & (MLPH - 1);
  float v = ld1(bias, j, bf);
#pragma unroll
  for (int kb = 0; kb < NKB; ++kb) v += part[(size_t)kb * Bsz * MLPH + g];
  st1(dout, g, bf, v);
}

extern "C" void kernel_launch(void* const* d_in, const int* in_sizes, int n_in,
                              void* d_out, int out_size, void* d_ws, size_t ws_size,
                              hipStream_t stream) {
  const void* enc  = d_in[0];                 // [64,1024,1024]
  const int*  lens = (const int*)d_in[1];     // [64]
  const void* cat  = d_in[3];                 // [64,1,512]
  const void* W1   = d_in[4];                 // [350,1536]
  const void* W2   = d_in[5];                 // [30,350]
  const void* Wm   = d_in[6];                 // [2048,46080]
  const void* bmlp = d_in[7];                 // [2048]

  // workspace layout (~114.1 MB, unchanged footprint)
  char*  wsb  = (char*)d_ws;
  int*   flag = (int*)wsb;
  float* s1   = (float*)(wsb + 1024);                    // 65536*352 fp32 = 92.27 MB
  float* Aws  = s1 + (size_t)65536 * S1LD;               // 64*30*1024 fp32 = 7.86 MB
  float* Mf   = Aws + (size_t)Bsz * R_ * Nsz;            // 64*46080 fp32 = 11.80 MB
  // aliases into dead regions (stream-ordered, no lifetime overlap):
  float* catW1 = Aws;   // written by k_cat, read by k_s1; Aws written later by k_s2
  float* part  = s1;    // s1 dead after k_s2; part (NKB*64*2048 fp32 = 16.8 MB) fits

  k_detect <<<1, 64, 0, stream>>>(enc, flag);
  k_cat    <<<DA_, 256, 0, stream>>>(cat, W1, catW1, flag);
  k_s1     <<<dim3(3, 512), 256, 0, stream>>>(enc, W1, catW1, lens, s1, flag);
  k_s2     <<<8192, 256, 0, stream>>>(s1, W2, lens, Aws, flag);
  k_softmax<<<Bsz * R_, 256, 0, stream>>>(Aws, d_out, flag);
  k_M      <<<dim3(6, Bsz), 256, 0, stream>>>(Aws, enc, cat, lens, Mf, flag);
  k_mlp    <<<dim3(MLPH / 64, NKB), 256, 0, stream>>>(Mf, Wm, part, flag);
  k_out    <<<512, 256, 0, stream>>>(part, bmlp, d_out, flag);
}